// Round 8
// baseline (470.584 us; speedup 1.0000x reference)
//
#include <hip/hip_runtime.h>
#include <hip/hip_bf16.h>

#define T_LEN 1024
#define D_DIM 64
#define BATCH 32

// ---------------------------------------------------------------------------
// Kernel 1: pairwise Euclidean distance, GEMM-trick.
// 128x128 tile, 256 threads, 8x8 micro-tile. UNCHANGED (counters surface
// once dp drops below it).
// ---------------------------------------------------------------------------
#define BM 128
#define BN 128

__global__ __launch_bounds__(256, 2) void cost_kernel(const float* __restrict__ pred,
                                                      const float* __restrict__ targ,
                                                      float* __restrict__ cost) {
    const int b = blockIdx.z;
    const float* P = pred + (size_t)b * T_LEN * D_DIM;
    const float* Tg = targ + (size_t)b * T_LEN * D_DIM;
    float* C = cost + (size_t)b * T_LEN * T_LEN;
    const int row0 = blockIdx.y * BM;
    const int col0 = blockIdx.x * BN;

    __shared__ __align__(16) float ps[BM][D_DIM + 4];
    __shared__ __align__(16) float ts[D_DIM][BN + 4];
    __shared__ float p2[BM], t2[BN];

    const int tid = threadIdx.x;

#pragma unroll
    for (int it = 0; it < 8; ++it) {
        int f = tid + 256 * it;
        int row = f >> 4;
        int kc = f & 15;
        float4 v = *(const float4*)(P + (size_t)(row0 + row) * D_DIM + 4 * kc);
        *(float4*)&ps[row][4 * kc] = v;
    }
#pragma unroll
    for (int it = 0; it < 8; ++it) {
        int f = tid + 256 * it;
        int col = f >> 4;
        int kc = f & 15;
        float4 w = *(const float4*)(Tg + (size_t)(col0 + col) * D_DIM + 4 * kc);
        ts[4 * kc + 0][col] = w.x;
        ts[4 * kc + 1][col] = w.y;
        ts[4 * kc + 2][col] = w.z;
        ts[4 * kc + 3][col] = w.w;
    }
    __syncthreads();

    if (tid < 128) {
        float s = 0.0f;
        const float4* pr = (const float4*)&ps[tid][0];
#pragma unroll
        for (int q = 0; q < 16; ++q) {
            float4 v = pr[q];
            s += v.x * v.x; s += v.y * v.y; s += v.z * v.z; s += v.w * v.w;
        }
        p2[tid] = s;
    } else {
        int c = tid - 128;
        float s = 0.0f;
#pragma unroll
        for (int k = 0; k < 64; ++k) { float x = ts[k][c]; s += x * x; }
        t2[c] = s;
    }
    __syncthreads();

    const int tx = tid & 15;
    const int ty = tid >> 4;
    const int cl = 4 * tx;
    const int ch = 64 + 4 * tx;

    float acc[8][8];
#pragma unroll
    for (int i = 0; i < 8; ++i)
#pragma unroll
        for (int j = 0; j < 8; ++j) acc[i][j] = 0.0f;

#pragma unroll
    for (int k4 = 0; k4 < 16; ++k4) {
        float4 bl[4], bh[4];
#pragma unroll
        for (int kk = 0; kk < 4; ++kk) {
            bl[kk] = *(const float4*)&ts[4 * k4 + kk][cl];
            bh[kk] = *(const float4*)&ts[4 * k4 + kk][ch];
        }
#pragma unroll
        for (int ih = 0; ih < 2; ++ih) {
#pragma unroll
            for (int i = 0; i < 4; ++i) {
                const int rr = (ih ? 64 + 4 * ty : 4 * ty) + i;
                float4 av = *(const float4*)&ps[rr][4 * k4];
                const float a4[4] = {av.x, av.y, av.z, av.w};
                float* A = acc[4 * ih + i];
#pragma unroll
                for (int kk = 0; kk < 4; ++kk) {
                    const float* blp = (const float*)&bl[kk];
                    const float* bhp = (const float*)&bh[kk];
                    const float ak = a4[kk];
#pragma unroll
                    for (int j = 0; j < 4; ++j) {
                        A[j]     += ak * blp[j];
                        A[4 + j] += ak * bhp[j];
                    }
                }
            }
        }
    }

    float4 tlo = *(const float4*)&t2[cl];
    float4 thi = *(const float4*)&t2[ch];
    const float* tl = (const float*)&tlo;
    const float* th = (const float*)&thi;
#pragma unroll
    for (int ih = 0; ih < 2; ++ih) {
#pragma unroll
        for (int i = 0; i < 4; ++i) {
            const int rr = (ih ? 64 + 4 * ty : 4 * ty) + i;
            const float pa = p2[rr];
            float* A = acc[4 * ih + i];
            float4 o1, o2;
            o1.x = sqrtf(fmaxf(pa + tl[0] - 2.0f * A[0], 1e-12f));
            o1.y = sqrtf(fmaxf(pa + tl[1] - 2.0f * A[1], 1e-12f));
            o1.z = sqrtf(fmaxf(pa + tl[2] - 2.0f * A[2], 1e-12f));
            o1.w = sqrtf(fmaxf(pa + tl[3] - 2.0f * A[3], 1e-12f));
            o2.x = sqrtf(fmaxf(pa + th[0] - 2.0f * A[4], 1e-12f));
            o2.y = sqrtf(fmaxf(pa + th[1] - 2.0f * A[5], 1e-12f));
            o2.z = sqrtf(fmaxf(pa + th[2] - 2.0f * A[6], 1e-12f));
            o2.w = sqrtf(fmaxf(pa + th[3] - 2.0f * A[7], 1e-12f));
            float* Crow = C + (size_t)(row0 + rr) * T_LEN + col0;
            *(float4*)(Crow + cl) = o1;
            *(float4*)(Crow + ch) = o2;
        }
    }
}

// ---------------------------------------------------------------------------
// Kernel 2: Frechet DP — SAME-WAVE LDS ring, drain amortized per SUPERSTEP.
// 2 buffers x 12 steps (96 KB). Superstep k: issue group k+1's 48
// global_load_lds (zero VGPR), take ONE explicit vmcnt(0) drain (~1000cy,
// amortized /12 steps), then consume 12 steps via plain C++ ring reads
// (precise compiler lgkmcnt; any additional conservative vmcnt(0)s are free
// once the counter is drained). Group k's data was issued a full superstep
// (~1800cy) ago -> resident. Same-wave program order = the round-2-validated
// protocol (absmax 0.0). No register pipeline, no cross-wave flags.
// Recurrence: max(c,min(min(up,left),diag)) == med3(left,c,max(c,min(up,diag)))
// — validated absmax=0 in rounds 3-6.
// ---------------------------------------------------------------------------
#define GSTEP 12

#define GLDS(SRC, LDSP, OFF)                                                  \
    __builtin_amdgcn_global_load_lds(                                         \
        (const __attribute__((address_space(1))) unsigned int*)(const void*)(SRC), \
        (__attribute__((address_space(3))) unsigned int*)(LDSP), 16, (OFF), 0)

__global__ __launch_bounds__(64, 1) void dp_kernel(const float* __restrict__ cost,
                                                   float* __restrict__ out) {
    const int b = blockIdx.x;
    const int t = threadIdx.x;  // lane 0..63
    const float INF = __builtin_inff();
    const float* Cb = cost + (size_t)b * T_LEN * T_LEN;

    // ring[buf][u][q][lane] = C[(12k+u)-lane][16*lane+4q .. +4)
    // gl_lds dest: uniform base + lane*16  -> [q][lane] slot.
    // consumer read: lane t reads [q][t]   -> contiguous 1KB wave read,
    // conflict-free b128 (measured 0 conflicts, rounds 2/7).
    __shared__ __align__(16) float4 ring[2][GSTEP][4][64];  // 96 KB

    float prev[16];
#pragma unroll
    for (int j = 0; j < 16; ++j) prev[j] = INF;
    float right_out = INF;
    float diag_feed = INF;

#define ISSUE_GROUP(G)                                                        \
    {                                                                         \
        const int base_ = (G) * GSTEP;                                        \
        float4(*buf_)[4][64] = ring[(G) & 1];                                 \
        _Pragma("unroll")                                                     \
        for (int u = 0; u < GSTEP; ++u) {                                     \
            int r_ = base_ + u - t;                                           \
            r_ = r_ < 0 ? 0 : (r_ > T_LEN - 1 ? T_LEN - 1 : r_);              \
            const float* src_ = Cb + (size_t)r_ * T_LEN + 16 * t;             \
            GLDS(src_, &buf_[u][0][0], 0);                                    \
            GLDS(src_, &buf_[u][1][0], 16);                                   \
            GLDS(src_, &buf_[u][2][0], 32);                                   \
            GLDS(src_, &buf_[u][3][0], 48);                                   \
        }                                                                     \
    }

    const int S = T_LEN + 63;                    // 1087 real steps
    const int NCH = (S + GSTEP - 1) / GSTEP;     // 91 supersteps (tail guarded)

    ISSUE_GROUP(0)

    int s = 0;
    for (int k = 0; k < NCH; ++k) {
        if (k + 1 < NCH) ISSUE_GROUP(k + 1)
        // One deterministic drain per superstep: completes group k (old) and
        // group k+1 (just issued). Budgeted ~1000cy / 12 steps.
        asm volatile("s_waitcnt vmcnt(0)" ::: "memory");
        const int buf = k & 1;
#pragma unroll
        for (int u = 0; u < GSTEP; ++u, ++s) {
            float4 q0 = ring[buf][u][0][t];
            float4 q1 = ring[buf][u][1][t];
            float4 q2 = ring[buf][u][2][t];
            float4 q3 = ring[buf][u][3][t];
            const int r = s - t;
            float inc = __shfl_up(right_out, 1, 64);
            float left = inc, diag = diag_feed;
            diag_feed = inc;
            if (t == 0) { left = (r == 0) ? -INF : INF; diag = INF; }
            if (r >= 0 && r < T_LEN) {
                float cq[16] = {q0.x, q0.y, q0.z, q0.w, q1.x, q1.y, q1.z, q1.w,
                                q2.x, q2.y, q2.z, q2.w, q3.x, q3.y, q3.z, q3.w};
                float gg[16];
                gg[0] = fmaxf(cq[0], fminf(prev[0], diag));
#pragma unroll
                for (int j = 1; j < 16; ++j)
                    gg[j] = fmaxf(cq[j], fminf(prev[j], prev[j - 1]));
                float v = left;
#pragma unroll
                for (int j = 0; j < 16; ++j) {
                    v = __builtin_amdgcn_fmed3f(v, cq[j], gg[j]);
                    prev[j] = v;
                }
                right_out = v;
            }
        }
    }
#undef ISSUE_GROUP

    if (t == 63) atomicAdd(out, prev[15] * (1.0f / (float)BATCH));
}

// ---------------------------------------------------------------------------
// Fallback: fused DP computing distances on the fly (only if ws can't hold
// one 4 MB cost matrix). Unchanged.
// ---------------------------------------------------------------------------
__global__ __launch_bounds__(64) void dp_fused_kernel(const float* __restrict__ pred,
                                                      const float* __restrict__ targ,
                                                      float* __restrict__ out) {
    const int b = blockIdx.x;
    const int t = threadIdx.x;
    const float INF = __builtin_inff();
    const float* P = pred + (size_t)b * T_LEN * D_DIM;
    const float* T = targ + (size_t)b * T_LEN * D_DIM + (size_t)(16 * t) * D_DIM;

    float prev[16];
#pragma unroll
    for (int j = 0; j < 16; ++j) prev[j] = INF;
    float right_out = INF;
    float diag_feed = INF;

    for (int s = 0; s < T_LEN + 63; s++) {
        int r = s - t;
        float inc = __shfl_up(right_out, 1, 64);
        float left = inc, diag = diag_feed;
        diag_feed = inc;
        if (t == 0) { left = (r == 0) ? -INF : INF; diag = INF; }
        if (r >= 0 && r < T_LEN) {
            float4 pr[16];
            const float4* pp = (const float4*)(P + (size_t)r * D_DIM);
#pragma unroll
            for (int q = 0; q < 16; q++) pr[q] = pp[q];
#pragma unroll
            for (int j = 0; j < 16; j++) {
                const float4* tp = (const float4*)(T + (size_t)j * D_DIM);
                float acc = 0.0f;
#pragma unroll
                for (int q = 0; q < 16; q++) {
                    float4 tv = tp[q];
                    float dx = pr[q].x - tv.x; acc += dx * dx;
                    float dy = pr[q].y - tv.y; acc += dy * dy;
                    float dz = pr[q].z - tv.z; acc += dz * dz;
                    float dw = pr[q].w - tv.w; acc += dw * dw;
                }
                float c = sqrtf(fmaxf(acc, 1e-12f));
                float up = prev[j];
                float v = fmaxf(c, fminf(fminf(up, diag), left));
                diag = up; left = v; prev[j] = v;
            }
            right_out = left;
        }
    }
    if (t == 63) atomicAdd(out, prev[15] * (1.0f / (float)BATCH));
}

extern "C" void kernel_launch(void* const* d_in, const int* in_sizes, int n_in,
                              void* d_out, int out_size, void* d_ws, size_t ws_size,
                              hipStream_t stream) {
    const float* pred = (const float*)d_in[0];
    const float* targ = (const float*)d_in[1];
    float* out = (float*)d_out;

    hipMemsetAsync(out, 0, sizeof(float) * out_size, stream);

    const size_t per_batch = (size_t)T_LEN * T_LEN * sizeof(float);  // 4 MB
    int bpg = (int)(ws_size / per_batch);
    if (bpg > BATCH) bpg = BATCH;

    if (bpg >= 1) {
        float* cost = (float*)d_ws;
        for (int g0 = 0; g0 < BATCH; g0 += bpg) {
            int gb = (BATCH - g0) < bpg ? (BATCH - g0) : bpg;
            dim3 grid(T_LEN / BN, T_LEN / BM, gb);
            cost_kernel<<<grid, 256, 0, stream>>>(pred + (size_t)g0 * T_LEN * D_DIM,
                                                  targ + (size_t)g0 * T_LEN * D_DIM,
                                                  cost);
            dp_kernel<<<gb, 64, 0, stream>>>(cost, out);
        }
    } else {
        dp_fused_kernel<<<BATCH, 64, 0, stream>>>(pred, targ, out);
    }
}